// Round 10
// baseline (7425.185 us; speedup 1.0000x reference)
//
#include <hip/hip_runtime.h>
#include <hip/hip_cooperative_groups.h>

namespace cg = cooperative_groups;

#define NB 4
#define NN 256
#define ND 128

// LDS layout (floats):
//  Wl    [16384]  W staged (64KB)
//  Al    [1024]   own 4 rows of A (in-place normalized adjacency)
//  xi    [128]    pivot row x[i,:]
//  prob  [256]
//  dinv  [256]
//  arow  [256]    published pivot row of A_prev (== column i by symmetry)
//  srow  [1024]   float4 per j: s_r = M[n0+r,j]*dinv[j]
//  ypart [2048]   float2 partials [wave][row][lane]
//  yrow  [512]    per-wave y row (also Xin row at init)
//  red   [8]      block reduction scratch
#define LDS_FLOATS 21896

__device__ __forceinline__ float2 ld2(const float* p) {
    return *reinterpret_cast<const float2*>(p);
}

// Per-batch flag barrier: block w release-publishes step i into its OWN flag
// word; wave 0 polls all 64 flags in parallel (4 cache lines, one latency)
// instead of 64 serialized RMWs on one counter. Monotonic step values ->
// no reset, no ABA. Fences identical to the proven round-9 protocol.
__device__ __forceinline__ void batch_barrier(int* flg, int step, int w) {
    __syncthreads();                 // all block stores drained (vmcnt(0) before s_barrier)
    if (threadIdx.x == 0) {
        __threadfence();             // release: agent-scope L2 writeback
        __hip_atomic_store(flg + w, step, __ATOMIC_RELAXED, __HIP_MEMORY_SCOPE_AGENT);
    }
    if (threadIdx.x < 64) {
        while (__hip_atomic_load(flg + threadIdx.x, __ATOMIC_RELAXED,
                                 __HIP_MEMORY_SCOPE_AGENT) < step)
            __builtin_amdgcn_s_sleep(2);
        __threadfence();             // acquire: invalidate L1/L2 (agent scope)
    }
    __syncthreads();
}

extern "C" __global__ void __launch_bounds__(256, 1)
gcn_coop_kernel(const float* __restrict__ Xin, const float* __restrict__ Wg,
                float* __restrict__ out, float* __restrict__ ws)
{
    extern __shared__ float lds[];
    float* Wl    = lds;            // 16384
    float* Al    = lds + 16384;    // 1024  (4 rows x 256)
    float* xi    = lds + 17408;    // 128
    float* prob  = lds + 17536;    // 256
    float* dinv  = lds + 17792;    // 256
    float* arow  = lds + 18048;    // 256
    float* srow  = lds + 18304;    // 1024
    float* ypart = lds + 19328;    // 2048
    float* yrow  = lds + 21376;    // 512
    float* red   = lds + 21888;    // 8

    const int tid  = threadIdx.x;
    const int lane = tid & 63;
    const int v    = tid >> 6;                 // wave id 0..3
    // XCD-confined mapping: batch b -> XCDs {2b, 2b+1} (blockIdx%8 == XCD heuristic)
    const int b    = (blockIdx.x & 7) >> 1;    // batch 0..3
    const int w    = (blockIdx.x & 1) * 32 + (blockIdx.x >> 3);  // 0..63
    const int n0   = w << 2;                   // first owned row
    const int nv   = n0 + v;                   // this wave's row

    float* X0  = ws;
    float* X1  = X0 + NB*NN*ND;
    float* R0  = X1 + NB*NN*ND;
    float* R1  = R0 + NB*NN;
    float* AR0 = R1 + NB*NN;
    float* AR1 = AR0 + NB*NN;
    int*   flg = (int*)(AR1 + NB*NN);          // flg[b*64 + w], monotonic step values

    // ---- stage W into LDS (once) ----
    {
        const float4* Wg4 = reinterpret_cast<const float4*>(Wg);
        float4* Wl4 = reinterpret_cast<float4*>(Wl);
        #pragma unroll
        for (int k = 0; k < 16; ++k) Wl4[tid + 256*k] = Wg4[tid + 256*k];
    }
    // stage own Xin row into yrow
    {
        const float2* src = reinterpret_cast<const float2*>(Xin + (b*NN + nv)*ND);
        reinterpret_cast<float2*>(yrow + v*ND)[lane] = src[lane];
    }
    // zero own arrival flag (published to all by the step-1 grid.sync)
    if (tid == 0) flg[b*64 + w] = 0;
    __syncthreads();

    // ---- init: x0 = relu(Xin @ W); Al = I-rows; rs0 = 1; arow(step1) = e_1; out diag = 1
    {
        float a0 = 0.f, a1 = 0.f;
        const float4* yr4 = reinterpret_cast<const float4*>(yrow + v*ND);
        #pragma unroll 4
        for (int dd = 0; dd < 32; ++dd) {
            float4 y4 = yr4[dd];
            float2 w0 = ld2(Wl + (4*dd+0)*ND + 2*lane);
            float2 w1 = ld2(Wl + (4*dd+1)*ND + 2*lane);
            float2 w2 = ld2(Wl + (4*dd+2)*ND + 2*lane);
            float2 w3 = ld2(Wl + (4*dd+3)*ND + 2*lane);
            a0 += y4.x*w0.x; a1 += y4.x*w0.y;
            a0 += y4.y*w1.x; a1 += y4.y*w1.y;
            a0 += y4.z*w2.x; a1 += y4.z*w2.y;
            a0 += y4.w*w3.x; a1 += y4.w*w3.y;
        }
        float2 r; r.x = fmaxf(a0, 0.f); r.y = fmaxf(a1, 0.f);
        reinterpret_cast<float2*>(X0 + (b*NN+nv)*ND)[lane] = r;
        #pragma unroll
        for (int rr = 0; rr < 4; ++rr)
            Al[rr*NN + tid] = (tid == n0 + rr) ? 1.f : 0.f;
        if (lane == 0) {
            R0[b*NN + nv] = 1.f;
            out[(b*NN+nv)*NN + nv] = 1.f;
        }
        if (w == 0) AR0[b*NN + tid] = (tid == 1) ? 1.f : 0.f;  // A0 row 1 = e_1
    }

    cg::grid_group grid = cg::this_grid();

    for (int i = 1; i < NN; ++i) {
        if (i == 1) grid.sync();                  // publishes init data AND zeroed flags
        else        batch_barrier(flg + b*64, i, w);
        const int cur = (i-1) & 1;
        const float* Xc  = cur ? X1 : X0;
        float*       Xn  = cur ? X0 : X1;
        const float* Rc  = cur ? R1 : R0;
        float*       Rn  = cur ? R0 : R1;
        const float* ARc = cur ? AR1 : AR0;
        float*       ARn = cur ? AR0 : AR1;

        // pivot row x[i,:] and published A-prev row i (== col i by symmetry)
        if (tid < 64)
            reinterpret_cast<float2*>(xi)[tid] =
                reinterpret_cast<const float2*>(Xc + (b*NN+i)*ND)[tid];
        arow[tid] = ARc[b*NN + tid];
        __syncthreads();

        // prob[t] = x[t]·x[i]  (t < i); deg partials for row i
        float pv = 0.f;
        if (tid < i) {
            const float4* xr  = reinterpret_cast<const float4*>(Xc + (b*NN+tid)*ND);
            const float4* xi4 = reinterpret_cast<const float4*>(xi);
            #pragma unroll 8
            for (int k = 0; k < 32; ++k) {
                float4 a = xr[k], c = xi4[k];
                pv += a.x*c.x; pv += a.y*c.y; pv += a.z*c.z; pv += a.w*c.w;
            }
        }
        float pd = (tid < i) ? (pv - arow[tid]) : 0.f;
        #pragma unroll
        for (int off = 32; off; off >>= 1) pd += __shfl_down(pd, off, 64);
        if (lane == 0) red[v] = pd;
        prob[tid] = pv;
        __syncthreads();

        // deg -> dinv (redundant in every block)
        {
            const float rc = Rc[b*NN + tid];
            float deg;
            if (tid < i)      deg = rc - arow[tid] + pv;
            else if (tid > i) deg = rc;
            else              deg = rc + red[0] + red[1] + red[2] + red[3];
            dinv[tid] = rsqrtf(deg);
        }
        __syncthreads();

        // ---- loop A: s[j] = M[n,j]*dinv[j]; update Al in place; adj_out row/col i
        {
            const int j = tid;
            const float dj = dinv[j];
            float sv[4];
            #pragma unroll
            for (int r = 0; r < 4; ++r) {
                const int n = n0 + r;
                float m;
                if (n == i)      m = (j < i) ? prob[j] : Al[r*NN + j];
                else if (j == i) m = (n < i) ? prob[n] : Al[r*NN + j];
                else             m = Al[r*NN + j];
                const float s = m * dj;
                sv[r] = s;
                Al[r*NN + j] = dinv[n] * s;   // in-place: same thread, same slot
                if (n == i && j < i) out[(b*NN+i)*NN + j] = prob[j];
            }
            if (j == i) {
                #pragma unroll
                for (int r = 0; r < 4; ++r) {
                    const int n = n0 + r;
                    if (n < i) out[(b*NN+n)*NN + i] = prob[n];
                }
            }
            reinterpret_cast<float4*>(srow)[j] = make_float4(sv[0], sv[1], sv[2], sv[3]);
        }
        __syncthreads();

        if (i < NN-1) {   // last step only needs adj_out updates
            // publish next pivot row A_next[i+1,:] (owner block only)
            {
                const unsigned rr = (unsigned)(i + 1 - n0);
                if (rr < 4u) ARn[b*NN + tid] = Al[rr*NN + tid];
            }
            // rs_next for own row: rs'[n] = dinv[n] * sum_j s[j]
            {
                float sacc = srow[lane*4 + v] + srow[(lane+64)*4 + v]
                           + srow[(lane+128)*4 + v] + srow[(lane+192)*4 + v];
                #pragma unroll
                for (int off = 32; off; off >>= 1) sacc += __shfl_down(sacc, off, 64);
                if (lane == 0) Rn[b*NN + nv] = dinv[nv] * sacc;
            }
            // ---- loop B: y partials; wave v covers j in [64v, 64v+64) for all 4 rows
            float y0x=0,y0y=0,y1x=0,y1y=0,y2x=0,y2y=0,y3x=0,y3y=0;
            const float2* Xc2   = reinterpret_cast<const float2*>(Xc + b*NN*ND);
            const float4* srow4 = reinterpret_cast<const float4*>(srow);
            #pragma unroll 4
            for (int jj = 0; jj < 64; ++jj) {
                const int jB = v*64 + jj;
                const float4 s  = srow4[jB];          // LDS broadcast
                const float2 xv = Xc2[jB*64 + lane];  // coalesced
                y0x += s.x*xv.x; y0y += s.x*xv.y;
                y1x += s.y*xv.x; y1y += s.y*xv.y;
                y2x += s.z*xv.x; y2y += s.z*xv.y;
                y3x += s.w*xv.x; y3y += s.w*xv.y;
            }
            float2* yp2 = reinterpret_cast<float2*>(ypart);
            yp2[(v*4+0)*64 + lane] = make_float2(y0x,y0y);
            yp2[(v*4+1)*64 + lane] = make_float2(y1x,y1y);
            yp2[(v*4+2)*64 + lane] = make_float2(y2x,y2y);
            yp2[(v*4+3)*64 + lane] = make_float2(y3x,y3y);
            __syncthreads();
            // reduce partials for own row, apply dinv[n]
            {
                float2 a  = yp2[(0*4+v)*64 + lane];
                float2 t1 = yp2[(1*4+v)*64 + lane];
                float2 t2 = yp2[(2*4+v)*64 + lane];
                float2 t3 = yp2[(3*4+v)*64 + lane];
                a.x += t1.x + t2.x + t3.x;
                a.y += t1.y + t2.y + t3.y;
                const float dn = dinv[nv];
                a.x *= dn; a.y *= dn;
                reinterpret_cast<float2*>(yrow + v*ND)[lane] = a;
            }
            // ---- loop C: x_next = relu(y @ W) ----
            {
                float a0 = 0.f, a1 = 0.f;
                const float4* yr4 = reinterpret_cast<const float4*>(yrow + v*ND);
                #pragma unroll 4
                for (int dd = 0; dd < 32; ++dd) {
                    float4 y4 = yr4[dd];
                    float2 w0 = ld2(Wl + (4*dd+0)*ND + 2*lane);
                    float2 w1 = ld2(Wl + (4*dd+1)*ND + 2*lane);
                    float2 w2 = ld2(Wl + (4*dd+2)*ND + 2*lane);
                    float2 w3 = ld2(Wl + (4*dd+3)*ND + 2*lane);
                    a0 += y4.x*w0.x; a1 += y4.x*w0.y;
                    a0 += y4.y*w1.x; a1 += y4.y*w1.y;
                    a0 += y4.z*w2.x; a1 += y4.z*w2.y;
                    a0 += y4.w*w3.x; a1 += y4.w*w3.y;
                }
                float2 r; r.x = fmaxf(a0, 0.f); r.y = fmaxf(a1, 0.f);
                reinterpret_cast<float2*>(Xn + (b*NN+nv)*ND)[lane] = r;
            }
        }
    }
}

extern "C" void kernel_launch(void* const* d_in, const int* in_sizes, int n_in,
                              void* d_out, int out_size, void* d_ws, size_t ws_size,
                              hipStream_t stream)
{
    const float* x  = (const float*)d_in[0];
    const float* W  = (const float*)d_in[1];
    float* out      = (float*)d_out;
    float* ws       = (float*)d_ws;
    (void)in_sizes; (void)n_in; (void)out_size; (void)ws_size;

    hipFuncSetAttribute(reinterpret_cast<const void*>(gcn_coop_kernel),
                        hipFuncAttributeMaxDynamicSharedMemorySize,
                        LDS_FLOATS * 4);

    void* args[] = { (void*)&x, (void*)&W, (void*)&out, (void*)&ws };
    hipLaunchCooperativeKernel(reinterpret_cast<void*>(gcn_coop_kernel),
                               dim3(NB*64), dim3(256),
                               args, LDS_FLOATS * 4, stream);
}

// Round 15
// 4288.181 us; speedup vs baseline: 1.7315x; 1.7315x over previous
//
#include <hip/hip_runtime.h>
#include <hip/hip_cooperative_groups.h>

namespace cg = cooperative_groups;

#define NB 4
#define NN 256
#define ND 128

// LDS layout (floats):
//  Wl    [16384]  W staged (64KB)
//  Al    [1024]   own 4 rows of A (in-place normalized adjacency)
//  xi    [128]    pivot row x[i,:]
//  prob  [256]
//  dinv  [256]
//  arow  [256]    published pivot row of A_prev (== column i by symmetry)
//  srow  [1024]   float4 per j: s_r = M[n0+r,j]*dinv[j]
//  ypart [2048]   float2 partials [wave][row][lane]
//  yrow  [512]    per-wave y row (also Xin row at init)
//  red   [8]      block reduction scratch
#define LDS_FLOATS 21896

__device__ __forceinline__ float2 ld2(const float* p) {
    return *reinterpret_cast<const float2*>(p);
}

// ---- coherence-point (agent-scope relaxed atomic) data access ----
// These bypass L1/L2 (proven cross-XCD coherent by the working round-9/10
// flag protocol), so NO buffer_wbl2/buffer_inv fences are needed anywhere.
__device__ __forceinline__ float2 ldc2(const float* p) {
    unsigned long long u = __hip_atomic_load((unsigned long long*)p,
                              __ATOMIC_RELAXED, __HIP_MEMORY_SCOPE_AGENT);
    union { unsigned long long u; float2 f; } c; c.u = u; return c.f;
}
__device__ __forceinline__ void stc2(float* p, float2 v) {
    union { unsigned long long u; float2 f; } c; c.f = v;
    __hip_atomic_store((unsigned long long*)p, c.u,
                       __ATOMIC_RELAXED, __HIP_MEMORY_SCOPE_AGENT);
}
__device__ __forceinline__ float ldc(const float* p) {
    unsigned u = __hip_atomic_load((unsigned*)p,
                    __ATOMIC_RELAXED, __HIP_MEMORY_SCOPE_AGENT);
    return __uint_as_float(u);
}
__device__ __forceinline__ void stc(float* p, float v) {
    __hip_atomic_store((unsigned*)p, __float_as_uint(v),
                       __ATOMIC_RELAXED, __HIP_MEMORY_SCOPE_AGENT);
}

// Fence-free per-batch barrier. __syncthreads() emits s_waitcnt vmcnt(0)
// before s_barrier (documented compiler behavior), so every block store --
// all of which are coherence-point atomics -- is acked before the flag is
// set. Readers' data loads are also coherence-point atomics, so no acquire
// invalidate is needed. Monotonic step values -> no reset, no ABA.
__device__ __forceinline__ void batch_barrier(int* flg, int step, int w) {
    __syncthreads();
    if (threadIdx.x == 0)
        __hip_atomic_store(flg + w, step, __ATOMIC_RELAXED, __HIP_MEMORY_SCOPE_AGENT);
    if (threadIdx.x < 64) {
        while (__hip_atomic_load(flg + threadIdx.x, __ATOMIC_RELAXED,
                                 __HIP_MEMORY_SCOPE_AGENT) < step)
            __builtin_amdgcn_s_sleep(1);
    }
    asm volatile("" ::: "memory");
    __syncthreads();
}

extern "C" __global__ void __launch_bounds__(256, 1)
gcn_coop_kernel(const float* __restrict__ Xin, const float* __restrict__ Wg,
                float* __restrict__ out, float* __restrict__ ws)
{
    extern __shared__ float lds[];
    float* Wl    = lds;            // 16384
    float* Al    = lds + 16384;    // 1024  (4 rows x 256)
    float* xi    = lds + 17408;    // 128
    float* prob  = lds + 17536;    // 256
    float* dinv  = lds + 17792;    // 256
    float* arow  = lds + 18048;    // 256
    float* srow  = lds + 18304;    // 1024
    float* ypart = lds + 19328;    // 2048
    float* yrow  = lds + 21376;    // 512
    float* red   = lds + 21888;    // 8

    const int tid  = threadIdx.x;
    const int lane = tid & 63;
    const int v    = tid >> 6;                 // wave id 0..3
    // XCD-confined mapping: batch b -> XCDs {2b, 2b+1} (blockIdx%8 == XCD heuristic)
    const int b    = (blockIdx.x & 7) >> 1;    // batch 0..3
    const int w    = (blockIdx.x & 1) * 32 + (blockIdx.x >> 3);  // 0..63
    const int n0   = w << 2;                   // first owned row
    const int nv   = n0 + v;                   // this wave's row

    float* X0  = ws;
    float* X1  = X0 + NB*NN*ND;
    float* R0  = X1 + NB*NN*ND;
    float* R1  = R0 + NB*NN;
    float* AR0 = R1 + NB*NN;
    float* AR1 = AR0 + NB*NN;
    int*   flg = (int*)(AR1 + NB*NN);          // flg[b*64 + w], monotonic step values

    // ---- stage W into LDS (once) ----
    {
        const float4* Wg4 = reinterpret_cast<const float4*>(Wg);
        float4* Wl4 = reinterpret_cast<float4*>(Wl);
        #pragma unroll
        for (int k = 0; k < 16; ++k) Wl4[tid + 256*k] = Wg4[tid + 256*k];
    }
    // stage own Xin row into yrow
    {
        const float2* src = reinterpret_cast<const float2*>(Xin + (b*NN + nv)*ND);
        reinterpret_cast<float2*>(yrow + v*ND)[lane] = src[lane];
    }
    // zero own arrival flag (published to all by the step-1 grid.sync)
    if (tid == 0)
        __hip_atomic_store(flg + b*64 + w, 0, __ATOMIC_RELAXED, __HIP_MEMORY_SCOPE_AGENT);
    __syncthreads();

    // ---- init: x0 = relu(Xin @ W); Al = I-rows; rs0 = 1; arow(step1) = e_1; out diag = 1
    {
        float a0 = 0.f, a1 = 0.f;
        const float4* yr4 = reinterpret_cast<const float4*>(yrow + v*ND);
        #pragma unroll 4
        for (int dd = 0; dd < 32; ++dd) {
            float4 y4 = yr4[dd];
            float2 w0 = ld2(Wl + (4*dd+0)*ND + 2*lane);
            float2 w1 = ld2(Wl + (4*dd+1)*ND + 2*lane);
            float2 w2 = ld2(Wl + (4*dd+2)*ND + 2*lane);
            float2 w3 = ld2(Wl + (4*dd+3)*ND + 2*lane);
            a0 += y4.x*w0.x; a1 += y4.x*w0.y;
            a0 += y4.y*w1.x; a1 += y4.y*w1.y;
            a0 += y4.z*w2.x; a1 += y4.z*w2.y;
            a0 += y4.w*w3.x; a1 += y4.w*w3.y;
        }
        float2 r; r.x = fmaxf(a0, 0.f); r.y = fmaxf(a1, 0.f);
        stc2(X0 + (b*NN+nv)*ND + 2*lane, r);
        #pragma unroll
        for (int rr = 0; rr < 4; ++rr)
            Al[rr*NN + tid] = (tid == n0 + rr) ? 1.f : 0.f;
        if (lane == 0) {
            stc(R0 + b*NN + nv, 1.f);
            out[(b*NN+nv)*NN + nv] = 1.f;
        }
        if (w == 0) stc(AR0 + b*NN + tid, (tid == 1) ? 1.f : 0.f);  // A0 row 1 = e_1
    }

    cg::grid_group grid = cg::this_grid();

    for (int i = 1; i < NN; ++i) {
        if (i == 1) grid.sync();                  // publishes init data AND zeroed flags
        else        batch_barrier(flg + b*64, i, w);
        const int cur = (i-1) & 1;
        const float* Xc  = cur ? X1 : X0;
        float*       Xn  = cur ? X0 : X1;
        const float* Rc  = cur ? R1 : R0;
        float*       Rn  = cur ? R0 : R1;
        const float* ARc = cur ? AR1 : AR0;
        float*       ARn = cur ? AR0 : AR1;

        // pivot row x[i,:] and published A-prev row i (== col i by symmetry)
        if (tid < 64) {
            float2 t = ldc2(Xc + (b*NN+i)*ND + 2*tid);
            reinterpret_cast<float2*>(xi)[tid] = t;
        }
        arow[tid] = ldc(ARc + b*NN + tid);
        __syncthreads();

        // prob[t] = x[t]·x[i]  (t < i); deg partials for row i
        float pv = 0.f;
        if (tid < i) {
            const float* xr = Xc + (b*NN+tid)*ND;
            float p0 = 0.f, p1 = 0.f;
            #pragma unroll 16
            for (int k = 0; k < 64; ++k) {
                float2 a = ldc2(xr + 2*k);
                p0 += a.x * xi[2*k];
                p1 += a.y * xi[2*k+1];
            }
            pv = p0 + p1;
        }
        float pd = (tid < i) ? (pv - arow[tid]) : 0.f;
        #pragma unroll
        for (int off = 32; off; off >>= 1) pd += __shfl_down(pd, off, 64);
        if (lane == 0) red[v] = pd;
        prob[tid] = pv;
        __syncthreads();

        // deg -> dinv (redundant in every block)
        {
            const float rc = ldc(Rc + b*NN + tid);
            float deg;
            if (tid < i)      deg = rc - arow[tid] + pv;
            else if (tid > i) deg = rc;
            else              deg = rc + red[0] + red[1] + red[2] + red[3];
            dinv[tid] = rsqrtf(deg);
        }
        __syncthreads();

        // ---- loop A: s[j] = M[n,j]*dinv[j]; update Al in place; adj_out row/col i
        {
            const int j = tid;
            const float dj = dinv[j];
            float sv[4];
            #pragma unroll
            for (int r = 0; r < 4; ++r) {
                const int n = n0 + r;
                float m;
                if (n == i)      m = (j < i) ? prob[j] : Al[r*NN + j];
                else if (j == i) m = (n < i) ? prob[n] : Al[r*NN + j];
                else             m = Al[r*NN + j];
                const float s = m * dj;
                sv[r] = s;
                Al[r*NN + j] = dinv[n] * s;   // in-place: same thread, same slot
                if (n == i && j < i) out[(b*NN+i)*NN + j] = prob[j];
            }
            if (j == i) {
                #pragma unroll
                for (int r = 0; r < 4; ++r) {
                    const int n = n0 + r;
                    if (n < i) out[(b*NN+n)*NN + i] = prob[n];
                }
            }
            reinterpret_cast<float4*>(srow)[j] = make_float4(sv[0], sv[1], sv[2], sv[3]);
        }
        __syncthreads();

        if (i < NN-1) {   // last step only needs adj_out updates
            // publish next pivot row A_next[i+1,:] (owner block only)
            {
                const unsigned rr = (unsigned)(i + 1 - n0);
                if (rr < 4u) stc(ARn + b*NN + tid, Al[rr*NN + tid]);
            }
            // rs_next for own row: rs'[n] = dinv[n] * sum_j s[j]
            {
                float sacc = srow[lane*4 + v] + srow[(lane+64)*4 + v]
                           + srow[(lane+128)*4 + v] + srow[(lane+192)*4 + v];
                #pragma unroll
                for (int off = 32; off; off >>= 1) sacc += __shfl_down(sacc, off, 64);
                if (lane == 0) stc(Rn + b*NN + nv, dinv[nv] * sacc);
            }
            // ---- loop B: y partials; wave v covers j in [64v, 64v+64) for all 4 rows
            float y0x=0,y0y=0,y1x=0,y1y=0,y2x=0,y2y=0,y3x=0,y3y=0;
            const float* XcB    = Xc + b*NN*ND;
            const float4* srow4 = reinterpret_cast<const float4*>(srow);
            #pragma unroll 8
            for (int jj = 0; jj < 64; ++jj) {
                const int jB = v*64 + jj;
                const float4 s  = srow4[jB];             // LDS broadcast
                const float2 xv = ldc2(XcB + jB*ND + 2*lane);  // coalesced, coherent
                y0x += s.x*xv.x; y0y += s.x*xv.y;
                y1x += s.y*xv.x; y1y += s.y*xv.y;
                y2x += s.z*xv.x; y2y += s.z*xv.y;
                y3x += s.w*xv.x; y3y += s.w*xv.y;
            }
            float2* yp2 = reinterpret_cast<float2*>(ypart);
            yp2[(v*4+0)*64 + lane] = make_float2(y0x,y0y);
            yp2[(v*4+1)*64 + lane] = make_float2(y1x,y1y);
            yp2[(v*4+2)*64 + lane] = make_float2(y2x,y2y);
            yp2[(v*4+3)*64 + lane] = make_float2(y3x,y3y);
            __syncthreads();
            // reduce partials for own row, apply dinv[n]
            {
                float2 a  = yp2[(0*4+v)*64 + lane];
                float2 t1 = yp2[(1*4+v)*64 + lane];
                float2 t2 = yp2[(2*4+v)*64 + lane];
                float2 t3 = yp2[(3*4+v)*64 + lane];
                a.x += t1.x + t2.x + t3.x;
                a.y += t1.y + t2.y + t3.y;
                const float dn = dinv[nv];
                a.x *= dn; a.y *= dn;
                reinterpret_cast<float2*>(yrow + v*ND)[lane] = a;
            }
            // ---- loop C: x_next = relu(y @ W) ----
            {
                float a0 = 0.f, a1 = 0.f;
                const float4* yr4 = reinterpret_cast<const float4*>(yrow + v*ND);
                #pragma unroll 4
                for (int dd = 0; dd < 32; ++dd) {
                    float4 y4 = yr4[dd];
                    float2 w0 = ld2(Wl + (4*dd+0)*ND + 2*lane);
                    float2 w1 = ld2(Wl + (4*dd+1)*ND + 2*lane);
                    float2 w2 = ld2(Wl + (4*dd+2)*ND + 2*lane);
                    float2 w3 = ld2(Wl + (4*dd+3)*ND + 2*lane);
                    a0 += y4.x*w0.x; a1 += y4.x*w0.y;
                    a0 += y4.y*w1.x; a1 += y4.y*w1.y;
                    a0 += y4.z*w2.x; a1 += y4.z*w2.y;
                    a0 += y4.w*w3.x; a1 += y4.w*w3.y;
                }
                float2 r; r.x = fmaxf(a0, 0.f); r.y = fmaxf(a1, 0.f);
                stc2(Xn + (b*NN+nv)*ND + 2*lane, r);
            }
        }
    }
}

extern "C" void kernel_launch(void* const* d_in, const int* in_sizes, int n_in,
                              void* d_out, int out_size, void* d_ws, size_t ws_size,
                              hipStream_t stream)
{
    const float* x  = (const float*)d_in[0];
    const float* W  = (const float*)d_in[1];
    float* out      = (float*)d_out;
    float* ws       = (float*)d_ws;
    (void)in_sizes; (void)n_in; (void)out_size; (void)ws_size;

    hipFuncSetAttribute(reinterpret_cast<const void*>(gcn_coop_kernel),
                        hipFuncAttributeMaxDynamicSharedMemorySize,
                        LDS_FLOATS * 4);

    void* args[] = { (void*)&x, (void*)&W, (void*)&out, (void*)&ws };
    hipLaunchCooperativeKernel(reinterpret_cast<void*>(gcn_coop_kernel),
                               dim3(NB*64), dim3(256),
                               args, LDS_FLOATS * 4, stream);
}